// Round 1
// baseline (200.250 us; speedup 1.0000x reference)
//
#include <hip/hip_runtime.h>
#include <cstring>
#include <cstdint>
#include <cmath>

// Problem constants (fixed by the reference): x is (64, 3, 384, 384) f32.
#define B_IMG 64
#define C_IMG 3
#define H_IMG 384
#define W_IMG 384
#define N_TOT (B_IMG * C_IMG * H_IMG * W_IMG)   // 28,311,552
#define N4    (N_TOT / 4)                        // 7,077,888

struct Rect { int t, b, l, r; };        // rows [t,b), cols [l,r); empty if t==b
struct Params { Rect rc[B_IMG]; };      // 1 KB, passed by value as kernarg

__host__ __device__ inline uint32_t rotl32(uint32_t x, uint32_t r) {
  return (x << r) | (x >> (32u - r));
}

// JAX threefry2x32 (20 rounds), bit-exact integer hash.
__host__ __device__ inline void tf2x32(uint32_t k0, uint32_t k1,
                                       uint32_t x0, uint32_t x1,
                                       uint32_t& o0, uint32_t& o1) {
  const uint32_t ks2 = k0 ^ k1 ^ 0x1BD11BDAu;
  x0 += k0; x1 += k1;
  x0 += x1; x1 = rotl32(x1, 13); x1 ^= x0;
  x0 += x1; x1 = rotl32(x1, 15); x1 ^= x0;
  x0 += x1; x1 = rotl32(x1, 26); x1 ^= x0;
  x0 += x1; x1 = rotl32(x1,  6); x1 ^= x0;
  x0 += k1; x1 += ks2 + 1u;
  x0 += x1; x1 = rotl32(x1, 17); x1 ^= x0;
  x0 += x1; x1 = rotl32(x1, 29); x1 ^= x0;
  x0 += x1; x1 = rotl32(x1, 16); x1 ^= x0;
  x0 += x1; x1 = rotl32(x1, 24); x1 ^= x0;
  x0 += ks2; x1 += k0 + 2u;
  x0 += x1; x1 = rotl32(x1, 13); x1 ^= x0;
  x0 += x1; x1 = rotl32(x1, 15); x1 ^= x0;
  x0 += x1; x1 = rotl32(x1, 26); x1 ^= x0;
  x0 += x1; x1 = rotl32(x1,  6); x1 ^= x0;
  x0 += k0; x1 += k1 + 3u;
  x0 += x1; x1 = rotl32(x1, 17); x1 ^= x0;
  x0 += x1; x1 = rotl32(x1, 29); x1 ^= x0;
  x0 += x1; x1 = rotl32(x1, 16); x1 ^= x0;
  x0 += x1; x1 = rotl32(x1, 24); x1 ^= x0;
  x0 += k1; x1 += ks2 + 4u;
  x0 += x1; x1 = rotl32(x1, 13); x1 ^= x0;
  x0 += x1; x1 = rotl32(x1, 15); x1 ^= x0;
  x0 += x1; x1 = rotl32(x1, 26); x1 ^= x0;
  x0 += x1; x1 = rotl32(x1,  6); x1 ^= x0;
  x0 += ks2; x1 += k0 + 5u;
  o0 = x0; o1 = x1;
}

// bits -> float in [0,1): bitcast((bits>>9)|0x3f800000) - 1.0f  (exact)
__host__ __device__ inline float unit_from_bits(uint32_t bits) {
  uint32_t fb = (bits >> 9) | 0x3f800000u;
  float f;
#ifdef __HIP_DEVICE_COMPILE__
  f = __uint_as_float(fb);
#else
  memcpy(&f, &fb, 4);
#endif
  return f - 1.0f;
}

// JAX partitionable-mode random bits for element idx (hi word of 64-bit iota
// is 0 for all our sizes): o0 ^ o1.
__host__ __device__ inline uint32_t rb_partitionable(uint32_t k0, uint32_t k1, uint32_t idx) {
  uint32_t o0, o1;
  tf2x32(k0, k1, 0u, idx, o0, o1);
  return o0 ^ o1;
}

// sqrt(2) * erfinv(u) matching XLA's f32 ErfInv expansion (Giles polynomial).
// Strict f32 ops (no contraction) so the tail matches the reference.
__device__ inline float noise_val(uint32_t idx, uint32_t kn0, uint32_t kn1) {
  const float LO = -0x1.fffffep-1f;           // nextafter(-1,0)
  uint32_t bits = rb_partitionable(kn0, kn1, idx);
  float f = unit_from_bits(bits);              // [0,1), exact
  // u = max(lo, f*(hi-lo) + lo); (hi-lo) in f32 == 2.0f exactly
  float u = __fadd_rn(__fmul_rn(f, 2.0f), LO);
  u = fmaxf(LO, u);
  float t  = __fmul_rn(u, u);
  float wv = -log1pf(-t);
  float p;
  if (wv < 5.0f) {
    float ww = __fadd_rn(wv, -2.5f);
    p = 2.81022636e-08f;
    p = __fadd_rn(__fmul_rn(p, ww),  3.43273939e-07f);
    p = __fadd_rn(__fmul_rn(p, ww), -3.5233877e-06f);
    p = __fadd_rn(__fmul_rn(p, ww), -4.39150654e-06f);
    p = __fadd_rn(__fmul_rn(p, ww),  0.00021858087f);
    p = __fadd_rn(__fmul_rn(p, ww), -0.00125372503f);
    p = __fadd_rn(__fmul_rn(p, ww), -0.00417768164f);
    p = __fadd_rn(__fmul_rn(p, ww),  0.246640727f);
    p = __fadd_rn(__fmul_rn(p, ww),  1.50140941f);
  } else {
    float ww = __fadd_rn(__fsqrt_rn(wv), -3.0f);
    p = -0.000200214257f;
    p = __fadd_rn(__fmul_rn(p, ww),  0.000100950558f);
    p = __fadd_rn(__fmul_rn(p, ww),  0.00134934322f);
    p = __fadd_rn(__fmul_rn(p, ww), -0.00367342844f);
    p = __fadd_rn(__fmul_rn(p, ww),  0.00573950773f);
    p = __fadd_rn(__fmul_rn(p, ww), -0.0076224613f);
    p = __fadd_rn(__fmul_rn(p, ww),  0.00943887047f);
    p = __fadd_rn(__fmul_rn(p, ww),  1.00167406f);
    p = __fadd_rn(__fmul_rn(p, ww),  2.83297682f);
  }
  float r = __fmul_rn(p, u);
  return __fmul_rn(1.41421356237f, r);        // np.float32(np.sqrt(2))
}

// Host-side: derive the 6 subkeys (fold-like split of key(42)) and the 64
// per-sample erase rectangles. Pure deterministic arithmetic, identical on
// every call (graph-capture safe). Strict f32 (contraction off).
static void compute_host_params(Params& P, uint32_t& kn0, uint32_t& kn1) {
#pragma clang fp contract(off)
  uint32_t keys[6][2];  // kp, ka, kr, kt, kl, kn
  for (uint32_t i = 0; i < 6; i++)
    tf2x32(0u, 42u, 0u, i, keys[i][0], keys[i][1]);
  kn0 = keys[5][0]; kn1 = keys[5][1];

  for (int b = 0; b < B_IMG; b++) {
    float u[5];
    for (int k = 0; k < 5; k++)
      u[k] = unit_from_bits(rb_partitionable(keys[k][0], keys[k][1], (uint32_t)b));

    float up = u[0];                            // uniform(kp): minval 0, maxval 1
    float da = 0.33f - 0.02f;
    float ua = u[1] * da;  ua = ua + 0.02f;  ua = fmaxf(0.02f, ua);
    float ta = ua * 147456.0f;                  // * area
    float dr = 3.3f - 0.3f;
    float ur = u[2] * dr;  ur = ur + 0.3f;   ur = fmaxf(0.3f, ur);

    float prod = ta * ur;
    float quot = ta / ur;
    int he = (int)rintf(sqrtf(prod));
    int we = (int)rintf(sqrtf(quot));
    bool valid = (up <= 0.5f) && (he < H_IMG) && (we < W_IMG);

    float th = u[3] * (float)(H_IMG - he + 1);
    float tl = u[4] * (float)(W_IMG - we + 1);
    int top  = (int)floorf(th);
    int left = (int)floorf(tl);

    if (valid) { P.rc[b].t = top;  P.rc[b].b = top + he; P.rc[b].l = left; P.rc[b].r = left + we; }
    else       { P.rc[b].t = 0;    P.rc[b].b = 0;        P.rc[b].l = 0;    P.rc[b].r = 0; }
  }
}

__global__ __launch_bounds__(256) void erase_norm_kernel(
    const float* __restrict__ x, const float* __restrict__ mean,
    const float* __restrict__ stdv, float* __restrict__ out,
    Params P, uint32_t kn0, uint32_t kn1) {
  int i4 = blockIdx.x * 256 + threadIdx.x;
  if (i4 >= N4) return;
  int base = i4 * 4;
  // 384 % 4 == 0 -> all 4 elements share (b,c,h)
  int w    = base % W_IMG;
  int rest = base / W_IMG;
  int h  = rest % H_IMG;
  int bc = rest / H_IMG;
  int c  = bc % C_IMG;
  int b  = bc / C_IMG;

  const float4 v = reinterpret_cast<const float4*>(x)[i4];
  float m  = mean[c];
  float sd = stdv[c];
  float4 o;
  o.x = (v.x - m) / sd;
  o.y = (v.y - m) / sd;
  o.z = (v.z - m) / sd;
  o.w = (v.w - m) / sd;

  Rect rc = P.rc[b];
  if (h >= rc.t && h < rc.b && w < rc.r && (w + 3) >= rc.l) {
    if (w     >= rc.l && w     < rc.r) o.x = noise_val((uint32_t)(base + 0), kn0, kn1);
    if (w + 1 >= rc.l && w + 1 < rc.r) o.y = noise_val((uint32_t)(base + 1), kn0, kn1);
    if (w + 2 >= rc.l && w + 2 < rc.r) o.z = noise_val((uint32_t)(base + 2), kn0, kn1);
    if (w + 3 >= rc.l && w + 3 < rc.r) o.w = noise_val((uint32_t)(base + 3), kn0, kn1);
  }
  reinterpret_cast<float4*>(out)[i4] = o;
}

extern "C" void kernel_launch(void* const* d_in, const int* in_sizes, int n_in,
                              void* d_out, int out_size, void* d_ws, size_t ws_size,
                              hipStream_t stream) {
  const float* x    = (const float*)d_in[0];
  const float* mean = (const float*)d_in[1];
  const float* stdv = (const float*)d_in[2];
  float* out = (float*)d_out;

  Params P;
  uint32_t kn0, kn1;
  compute_host_params(P, kn0, kn1);

  int blocks = (N4 + 255) / 256;   // 27648
  erase_norm_kernel<<<blocks, 256, 0, stream>>>(x, mean, stdv, out, P, kn0, kn1);
}